// Round 6
// baseline (178.415 us; speedup 1.0000x reference)
//
#include <hip/hip_runtime.h>
#include <hip/hip_bf16.h>

// Problem constants (fixed by the reference)
#define B_  16
#define LQ_ 1024
#define LK_ 1024
#define C_  512

typedef __attribute__((ext_vector_type(4))) float f32x4;
typedef __attribute__((ext_vector_type(8))) short bf16x8;

__device__ __forceinline__ float bf2f(ushort u) {
  union { unsigned int i; float f; } v; v.i = ((unsigned int)u) << 16; return v.f;
}
__device__ __forceinline__ ushort f2bf(float f) {
  union { float f; unsigned int i; } v; v.f = f;
  unsigned int r = v.i + 0x7fffu + ((v.i >> 16) & 1u);
  return (ushort)(r >> 16);
}
__device__ __forceinline__ float gelu_exact(float x) {
  return 0.5f * x * (1.0f + erff(x * 0.70710678118654752f));
}

// async global->LDS, 16B per lane; LDS dest is wave-uniform base + lane*16.
__device__ __forceinline__ void gload_lds16(const ushort* g, ushort* l) {
  __builtin_amdgcn_global_load_lds(
      (const __attribute__((address_space(1))) void*)g,
      (__attribute__((address_space(3))) void*)l, 16, 0, 0);
}

#define VMCNT(n) asm volatile("s_waitcnt vmcnt(" #n ")" ::: "memory")
#define BARRIER() asm volatile("s_barrier" ::: "memory")

// ---------------------------------------------------------------------------
// prep: fp32 row (len 512) -> bf16 row + fp32 L2 norm (of ORIGINAL values)
__global__ __launch_bounds__(256) void prep_qk(const float* __restrict__ x,
                                               ushort* __restrict__ xb,
                                               float* __restrict__ norms) {
  int wid = blockIdx.x * 4 + (threadIdx.x >> 6);
  int lane = threadIdx.x & 63;
  const float* xr = x + (long)wid * C_;
  ushort* xo = xb + (long)wid * C_;
  float ss = 0.f;
#pragma unroll
  for (int i0 = 0; i0 < 2; ++i0) {
    int i = lane * 4 + i0 * 256;
    float4 v = *(const float4*)(xr + i);
    ss += v.x * v.x + v.y * v.y + v.z * v.z + v.w * v.w;
    ushort4 o;
    o.x = f2bf(v.x); o.y = f2bf(v.y); o.z = f2bf(v.z); o.w = f2bf(v.w);
    *(ushort4*)(xo + i) = o;
  }
#pragma unroll
  for (int off = 32; off > 0; off >>= 1) ss += __shfl_xor(ss, off);
  if (lane == 0) norms[wid] = sqrtf(ss);
}

// fp32 -> bf16 elementwise (n4 float4 chunks)
__global__ __launch_bounds__(256) void conv_bf16(const float* __restrict__ x,
                                                 ushort* __restrict__ o, int n4) {
  int i = blockIdx.x * 256 + threadIdx.x;
  if (i < n4) {
    float4 v = *(const float4*)(x + (long)i * 4);
    ushort4 u;
    u.x = f2bf(v.x); u.y = f2bf(v.y); u.z = f2bf(v.z); u.w = f2bf(v.w);
    *(ushort4*)(o + (long)i * 4) = u;
  }
}

// ---------------------------------------------------------------------------
// Batched NT GEMM, 256x256 tile, BK=64, 512 threads = 8 waves (2M x 4N).
// Read-ahead pipeline: per K-tile 4 phases (= C quadrants q00,q01,q10,q11).
// Every MFMA operand is a register loaded ONE phase earlier (rotation
// aaA/aaB/bA/bB); per-phase ds_reads balanced 4/8/8/4; 2 gloads staged per
// phase; counted vmcnt (P0:2, P2:4, P3:4) always waits on loads 2 phases
// old and never drains in the main loop; ONE s_barrier per phase; NO
// explicit lgkm waits (compiler emits precise partial lgkmcnt).
// Slots: s covers LDS rows [64s,64s+64). A: aaE={A0,A2}, aaO={A1,A3}.
// B rows remapped l = nh*128 + wc*32 + ni*16 + l16: b0={B0,B1}, b1={B2,B3}.
// Stage order/tile: P0:A0',A2'  P1:B0',B1'  P2:A1',A3'  P3:B2',B3'.
// Read order/tile:  P0:b1(cur)  P1:aaO(cur) P2:aaE'(nxt) P3:b0'(nxt).
// 16B-chunk XOR swizzle cb = g ^ (row&7) on global source + ds_read addr;
// LDS dest linear (rule 21); measured 0 bank conflicts.
// EPI 0: v/(qn*kn+1e-2) -> bf16.  EPI 1: gelu -> bf16.
// EPI 2: no C store; fused row-dot with w3 -> atomicAdd into wv.
template <int EPI>
__global__ __launch_bounds__(512, 2) void gemm256(
    const ushort* __restrict__ A, const ushort* __restrict__ Bm,
    ushort* __restrict__ Cc, int K, long sA, long sB, long sC,
    const float* __restrict__ qn, const float* __restrict__ kn,
    const float* __restrict__ w3v, float* __restrict__ wv) {
  // XCD-aware block swizzle: grid = 256, 256 % 8 == 0 -> bijective
  int per = (int)(gridDim.x >> 3);
  int orig = blockIdx.x;
  int id = (orig & 7) * per + (orig >> 3);
  int b = id >> 4;              // 16 tiles per batch (4x4)
  int rt = id & 15;
  const int bm = (rt >> 2) * 256, bn = (rt & 3) * 256;

  A += (long)b * sA + (long)bm * K;   // fold bm into A base
  Bm += (long)b * sB;

  __shared__ ushort At[2][256 * 64];
  __shared__ ushort Bt[2][256 * 64];

  const int tid = threadIdx.x;
  const int lane = tid & 63, w = tid >> 6;
  const int wr = w >> 2, wc = w & 3;          // 2 x 4 wave grid
  const int l16 = lane & 15, lhi = lane >> 4;

  f32x4 acc[8][4] = {};

  // staging slots: slot s covers LDS rows [s*64, s*64+64) of one operand.
  const ushort* gAs[4];
  const ushort* gBs[4];
  int dstc[4];
#pragma unroll
  for (int s = 0; s < 4; ++s) {
    int c = s * 512 + tid;          // chunk index (16B units)
    int l = c >> 3;                 // LDS row
    int cb = (c & 7) ^ (l & 7);     // swizzled source column chunk
    gAs[s] = A + (long)l * K + cb * 8;
    int nh = l >> 7, wcb = (l >> 5) & 3, jj = l & 31;
    int rb = wcb * 64 + nh * 32 + jj;   // global B row for LDS row l
    gBs[s] = Bm + (long)(bn + rb) * K + cb * 8;
    dstc[s] = (s * 512 + (tid & ~63)) * 8;  // ushort offset (wave-uniform)
  }

  // prologue: stage tile 0 into buf 0, drain, pre-read aaA (aaE) + bA (b0)
  {
    ushort* Ad = &At[0][0];
    ushort* Bd = &Bt[0][0];
#pragma unroll
    for (int s = 0; s < 4; ++s) {
      gload_lds16(gAs[s], Ad + dstc[s]);
      gload_lds16(gBs[s], Bd + dstc[s]);
    }
  }
  VMCNT(0);
  BARRIER();

  const int xk0 = (lhi ^ (l16 & 7)) * 8;
  const int xk1 = ((4 + lhi) ^ (l16 & 7)) * 8;

  bf16x8 aaA[4][2], aaB[4][2], bA[2][2], bB[2][2];
#pragma unroll
  for (int mi = 0; mi < 4; ++mi) {
    int r = wr * 128 + mi * 16 + l16;
    aaA[mi][0] = *(const bf16x8*)(&At[0][0] + r * 64 + xk0);
    aaA[mi][1] = *(const bf16x8*)(&At[0][0] + r * 64 + xk1);
  }
#pragma unroll
  for (int ni = 0; ni < 2; ++ni) {
    int lb = wc * 32 + ni * 16 + l16;
    bA[ni][0] = *(const bf16x8*)(&Bt[0][0] + lb * 64 + xk0);
    bA[ni][1] = *(const bf16x8*)(&Bt[0][0] + lb * 64 + xk1);
  }

#define MFMA_QUAD(MH, NH, AA, BB)                                          \
  __builtin_amdgcn_s_setprio(1);                                           \
  _Pragma("unroll") for (int mi = 0; mi < 4; ++mi)                         \
      _Pragma("unroll") for (int ni = 0; ni < 2; ++ni)                     \
          _Pragma("unroll") for (int kk = 0; kk < 2; ++kk)                 \
              acc[(MH)*4 + mi][(NH)*2 + ni] =                              \
      __builtin_amdgcn_mfma_f32_16x16x32_bf16(                             \
          AA[mi][kk], BB[ni][kk], acc[(MH)*4 + mi][(NH)*2 + ni], 0, 0, 0); \
  __builtin_amdgcn_s_setprio(0);

  const int nt = K / 64;
  int cur = 0;
  for (int t = 0; t < nt; ++t) {
    const ushort* Ac = &At[cur][0];
    const ushort* Bc = &Bt[cur][0];
    ushort* Ad = &At[cur ^ 1][0];
    ushort* Bd = &Bt[cur ^ 1][0];
    const int ko = (t + 1) * 64;
    const bool pf = (t + 1 < nt);

    // ---- P0: stage A0',A2'; vmcnt; BAR; read b1(cur)->bB; q00(aaA,bA)
    if (pf) {
      gload_lds16(gAs[0] + ko, Ad + dstc[0]);
      gload_lds16(gAs[2] + ko, Ad + dstc[2]);
      VMCNT(2);
    } else {
      VMCNT(0);
    }
    BARRIER();
#pragma unroll
    for (int ni = 0; ni < 2; ++ni) {
      int lb = 128 + wc * 32 + ni * 16 + l16;
      bB[ni][0] = *(const bf16x8*)(Bc + lb * 64 + xk0);
      bB[ni][1] = *(const bf16x8*)(Bc + lb * 64 + xk1);
    }
    MFMA_QUAD(0, 0, aaA, bA)

    // ---- P1: stage B0',B1'; BAR; read aaO(cur)->aaB; q01(aaA,bB)
    if (pf) {
      gload_lds16(gBs[0] + ko, Bd + dstc[0]);
      gload_lds16(gBs[1] + ko, Bd + dstc[1]);
    }
    BARRIER();
#pragma unroll
    for (int mi = 0; mi < 4; ++mi) {
      int r = wr * 128 + 64 + mi * 16 + l16;
      aaB[mi][0] = *(const bf16x8*)(Ac + r * 64 + xk0);
      aaB[mi][1] = *(const bf16x8*)(Ac + r * 64 + xk1);
    }
    MFMA_QUAD(0, 1, aaA, bB)

    // ---- P2: stage A1',A3'; vmcnt(4); BAR; read aaE'(nxt)->aaA; q10(aaB,bA)
    if (pf) {
      gload_lds16(gAs[1] + ko, Ad + dstc[1]);
      gload_lds16(gAs[3] + ko, Ad + dstc[3]);
      VMCNT(4);
    }
    BARRIER();
    if (pf) {
#pragma unroll
      for (int mi = 0; mi < 4; ++mi) {
        int r = wr * 128 + mi * 16 + l16;
        aaA[mi][0] = *(const bf16x8*)(Ad + r * 64 + xk0);
        aaA[mi][1] = *(const bf16x8*)(Ad + r * 64 + xk1);
      }
    }
    MFMA_QUAD(1, 0, aaB, bA)

    // ---- P3: stage B2',B3'; vmcnt(4); BAR; read b0'(nxt)->bA; q11(aaB,bB)
    if (pf) {
      gload_lds16(gBs[2] + ko, Bd + dstc[2]);
      gload_lds16(gBs[3] + ko, Bd + dstc[3]);
      VMCNT(4);
    }
    BARRIER();
    if (pf) {
#pragma unroll
      for (int ni = 0; ni < 2; ++ni) {
        int lb = wc * 32 + ni * 16 + l16;
        bA[ni][0] = *(const bf16x8*)(Bd + lb * 64 + xk0);
        bA[ni][1] = *(const bf16x8*)(Bd + lb * 64 + xk1);
      }
    }
    MFMA_QUAD(1, 1, aaB, bB)

    cur ^= 1;
  }
#undef MFMA_QUAD

  // epilogue (C/D layout: col = lane&15, row = (lane>>4)*4 + reg)
  if constexpr (EPI == 2) {
    float* wvb = wv + (long)b * LQ_;
    float w3c[4];
#pragma unroll
    for (int n = 0; n < 4; ++n) w3c[n] = w3v[bn + wc * 64 + n * 16 + l16];
#pragma unroll
    for (int m = 0; m < 8; ++m)
#pragma unroll
      for (int rr = 0; rr < 4; ++rr) {
        float s = 0.f;
#pragma unroll
        for (int n = 0; n < 4; ++n)
          s += gelu_exact(acc[m][n][rr]) * w3c[n];
        s += __shfl_xor(s, 1);
        s += __shfl_xor(s, 2);
        s += __shfl_xor(s, 4);
        s += __shfl_xor(s, 8);
        if (l16 == 0)
          atomicAdd(&wvb[bm + wr * 128 + m * 16 + lhi * 4 + rr], s);
      }
  } else {
    Cc += (long)b * sC;
    const float* qnb = qn + (long)b * LQ_;
    const float* knb = kn + (long)b * LK_;
#pragma unroll
    for (int m = 0; m < 8; ++m) {
      int row0 = bm + wr * 128 + m * 16 + lhi * 4;
#pragma unroll
      for (int n = 0; n < 4; ++n) {
        int col = bn + wc * 64 + n * 16 + l16;
#pragma unroll
        for (int rr = 0; rr < 4; ++rr) {
          float v = acc[m][n][rr];
          int grow = row0 + rr;
          if (EPI == 0) {
            v = v / (qnb[grow] * knb[col] + 1e-2f);
          } else {
            v = gelu_exact(v);
          }
          Cc[(long)grow * 1024 + col] = f2bf(v);
        }
      }
    }
  }
}

// ---------------------------------------------------------------------------
// partial: wraw[b,k] += sum_{q in chunk} wv[b,q] * S[b,q,k]
__global__ __launch_bounds__(256) void gate_partial(const ushort* __restrict__ S,
                                                    const float* __restrict__ wv,
                                                    float* __restrict__ wraw) {
  int b = blockIdx.z;
  int k = blockIdx.x * 256 + threadIdx.x;
  int q0 = blockIdx.y * 128;
  const ushort* Sb = S + (long)b * LQ_ * LK_;
  const float* wb = wv + b * LQ_;
  float acc = 0.f;
#pragma unroll 4
  for (int q = q0; q < q0 + 128; ++q) acc += wb[q] * bf2f(Sb[(long)q * LK_ + k]);
  atomicAdd(&wraw[b * LK_ + k], acc);
}

// out[b,k,c] = value * (1 + tanh(wraw/32)); one float4 per thread
__global__ __launch_bounds__(256) void finalize(const float* __restrict__ value,
                                                const float* __restrict__ wraw,
                                                float* __restrict__ out) {
  long i = (long)blockIdx.x * 256 + threadIdx.x;  // float4 index
  long e = i * 4;
  int row = (int)(e >> 9);  // / 512
  float g = 1.f + tanhf(wraw[row] * (1.f / 32.f));
  float4 v = ((const float4*)value)[i];
  v.x *= g; v.y *= g; v.z *= g; v.w *= g;
  ((float4*)out)[i] = v;
}

// ---------------------------------------------------------------------------
extern "C" void kernel_launch(void* const* d_in, const int* in_sizes, int n_in,
                              void* d_out, int out_size, void* d_ws,
                              size_t ws_size, hipStream_t stream) {
  const float* query = (const float*)d_in[0];
  const float* key   = (const float*)d_in[1];
  const float* value = (const float*)d_in[2];
  const float* w1    = (const float*)d_in[3];
  const float* w2    = (const float*)d_in[4];
  const float* w3    = (const float*)d_in[5];
  float* out = (float*)d_out;

  // workspace layout (bytes)
  const size_t QB_BYTES = (size_t)B_ * LQ_ * C_ * 2;       // 16 MB
  const size_t S_BYTES  = (size_t)B_ * LQ_ * LK_ * 2;      // 32 MB
  const size_t W_BYTES  = (size_t)LK_ * LK_ * 2;           // 2 MB
  const size_t OFF_QB = 0;
  const size_t OFF_KB = OFF_QB + QB_BYTES;
  const size_t OFF_S  = OFF_KB + QB_BYTES;
  const size_t OFF_H1 = OFF_S + S_BYTES;
  const size_t OFF_W1 = OFF_H1 + S_BYTES;
  const size_t OFF_W2 = OFF_W1 + W_BYTES;
  const size_t OFF_QN = OFF_W2 + W_BYTES;
  const size_t OFF_KN = OFF_QN + (size_t)B_ * LQ_ * 4;
  const size_t OFF_WV = OFF_KN + (size_t)B_ * LK_ * 4;
  const size_t OFF_WR = OFF_WV + (size_t)B_ * LQ_ * 4;
  const size_t TOTAL  = OFF_WR + (size_t)B_ * LK_ * 4;
  if (ws_size < TOTAL) return;  // workspace too small; fail visibly

  char* ws = (char*)d_ws;
  ushort* Qb  = (ushort*)(ws + OFF_QB);
  ushort* Kb  = (ushort*)(ws + OFF_KB);
  ushort* S   = (ushort*)(ws + OFF_S);
  ushort* h1  = (ushort*)(ws + OFF_H1);
  ushort* W1b = (ushort*)(ws + OFF_W1);
  ushort* W2b = (ushort*)(ws + OFF_W2);
  float* qn   = (float*)(ws + OFF_QN);
  float* kn   = (float*)(ws + OFF_KN);
  float* wv   = (float*)(ws + OFF_WV);
  float* wraw = (float*)(ws + OFF_WR);

  // 1) prep: bf16 casts + norms
  prep_qk<<<dim3(B_ * LQ_ / 4), 256, 0, stream>>>(query, Qb, qn);
  prep_qk<<<dim3(B_ * LK_ / 4), 256, 0, stream>>>(key, Kb, kn);
  conv_bf16<<<dim3(LK_ * LK_ / 4 / 256), 256, 0, stream>>>(w1, W1b, LK_ * LK_ / 4);
  conv_bf16<<<dim3(LK_ * LK_ / 4 / 256), 256, 0, stream>>>(w2, W2b, LK_ * LK_ / 4);
  hipMemsetAsync(wraw, 0, (size_t)B_ * LK_ * 4, stream);
  hipMemsetAsync(wv, 0, (size_t)B_ * LQ_ * 4, stream);

  // 2) S = (Q K^T) / (|q||k| + 1e-2), bf16
  gemm256<0><<<dim3(256), 512, 0, stream>>>(
      Qb, Kb, S, C_, (long)LQ_ * C_, (long)LK_ * C_, (long)LQ_ * LK_,
      qn, kn, nullptr, nullptr);

  // 3) h1 = gelu(S @ W1^T)
  gemm256<1><<<dim3(256), 512, 0, stream>>>(
      S, W1b, h1, LK_, (long)LQ_ * LK_, 0L, (long)LQ_ * LK_,
      nullptr, nullptr, nullptr, nullptr);

  // 4) fused: wv[b,q] = dot(gelu(h1 @ W2^T)[q,:], w3)  (h2 never stored)
  gemm256<2><<<dim3(256), 512, 0, stream>>>(
      h1, W2b, nullptr, LK_, (long)LQ_ * LK_, 0L, 0L,
      nullptr, nullptr, w3, wv);

  // 5) wraw[b,k] = sum_q wv[b,q] * S[b,q,k]
  gate_partial<<<dim3(LK_ / 256, LQ_ / 128, B_), 256, 0, stream>>>(S, wv, wraw);

  // 6) out = value * (1 + tanh(wraw/32))
  finalize<<<dim3((size_t)B_ * LK_ * C_ / 4 / 256), 256, 0, stream>>>(value, wraw, out);
}